// Round 2
// baseline (2157.189 us; speedup 1.0000x reference)
//
#include <hip/hip_runtime.h>

// Problem constants
#define TDEC 50
#define NB   32
#define NPTS 512     // N (pointer candidates)
#define DEMB 512
#define DENC 1024
#define DDEC 1024
#define G4   4096    // 4*DDEC (lstm gates)

__device__ __forceinline__ float sigf(float x) {
  float e = __expf(-fabsf(x));
  float r = 1.0f / (1.0f + e);
  return x >= 0.0f ? r : 1.0f - r;
}
__device__ __forceinline__ float tanh_(float x) {
  return 2.0f * sigf(2.0f * x) - 1.0f;   // tanh(x) = 2*sigmoid(2x)-1
}

// ---------------- small prep kernels ----------------

// first-occurrence index of n in gt[b,:]  (ft < t  <=>  picked at step t)
__global__ void k_first(const int* __restrict__ gt, int* __restrict__ ft) {
  int idx = blockIdx.x * blockDim.x + threadIdx.x;
  if (idx >= NB * NPTS) return;
  int b = idx >> 9, n = idx & (NPTS - 1);
  int first = TDEC;
  for (int t = 0; t < TDEC; ++t) {
    int g = gt[b * TDEC + t];
    if (g == n && t < first) first = t;
  }
  ft[idx] = first;
}

// teacher-forced LSTM inputs: Xin[t][b][d] = (t==0) ? go[d] : emb[b, gt[b,t-1], d]
__global__ void k_gather(const float* __restrict__ emb, const int* __restrict__ gt,
                         const float* __restrict__ go, float* __restrict__ Xin) {
  int idx = blockIdx.x * blockDim.x + threadIdx.x;
  if (idx >= TDEC * NB * DEMB) return;
  int d = idx & (DEMB - 1);
  int tb = idx >> 9;
  int b = tb & (NB - 1);
  int t = tb >> 5;
  float v;
  if (t == 0) v = go[d];
  else {
    int g = gt[b * TDEC + (t - 1)];
    v = emb[((long long)b * NPTS + g) * DEMB + d];
  }
  Xin[idx] = v;
}

// ---------------- generic fp32 tiled GEMM ----------------
// C[m,n] = sum_k Aop[m,k] * Bop[k,n]   (per batch z)
//   Aop[m,k] = (k < kSplit) ? A[m*lda + k] : A2[m*lda2 + k - kSplit]   (k-contig)
//   BT=true : Bop[k,n] = B[n*ldb + k]   (k-contig rows, i.e. C = A*B^T)
//   BT=false: Bop[k,n] = B[k*ldb + n]   (n-contig rows)
// EPI: 0 = optional bias1/bias2 over n; 1 = pointer-score epilogue.
struct GemmP {
  const float* A; long long aBatch; int lda;
  const float* A2; int lda2; int kSplit;
  const float* B; long long bBatch; int ldb;
  float* C; long long cBatch; long long ldcM; long long ldcN;
  int M, N, K;
  const float* bias1; const float* bias2;
  const int* ft; const float* emb_mask;
};

template <bool BT, int EPI>
__global__ __launch_bounds__(256) void k_gemm(GemmP p) {
  __shared__ float As[16][68];
  __shared__ float Bs[16][68];
  const int z = blockIdx.z;
  const float* A = p.A + (long long)z * p.aBatch;
  const float* B = p.B + (long long)z * p.bBatch;
  const int m0 = blockIdx.x * 64, n0 = blockIdx.y * 64;
  const int tid = threadIdx.x;
  const int lm = tid >> 2;        // 0..63
  const int lk = (tid & 3) << 2;  // 0,4,8,12
  const int kr = tid >> 4;        // NN loader: k row 0..15
  const int nq = tid & 15;        // NN loader: n quad
  const int tm = tid & 15, tn = tid >> 4;
  float acc[4][4] = {};
  for (int k0 = 0; k0 < p.K; k0 += 16) {
    float4 av = make_float4(0.f, 0.f, 0.f, 0.f);
    float4 bv = make_float4(0.f, 0.f, 0.f, 0.f);
    {
      int am = m0 + lm, kk = k0 + lk;
      if (am < p.M) {
        av = (kk < p.kSplit)
               ? *(const float4*)(A + (long long)am * p.lda + kk)
               : *(const float4*)(p.A2 + (long long)am * p.lda2 + (kk - p.kSplit));
      }
    }
    if (BT) {
      int bn = n0 + lm, kk = k0 + lk;
      if (bn < p.N) bv = *(const float4*)(B + (long long)bn * p.ldb + kk);
    } else {
      int bn = n0 + (nq << 2), kk = k0 + kr;
      if (bn + 3 < p.N) bv = *(const float4*)(B + (long long)kk * p.ldb + bn);
    }
    __syncthreads();
    As[lk + 0][lm] = av.x; As[lk + 1][lm] = av.y;
    As[lk + 2][lm] = av.z; As[lk + 3][lm] = av.w;
    if (BT) {
      Bs[lk + 0][lm] = bv.x; Bs[lk + 1][lm] = bv.y;
      Bs[lk + 2][lm] = bv.z; Bs[lk + 3][lm] = bv.w;
    } else {
      *(float4*)&Bs[kr][nq << 2] = bv;
    }
    __syncthreads();
#pragma unroll
    for (int kk = 0; kk < 16; ++kk) {
      float4 a = *(const float4*)&As[kk][tm << 2];
      float4 b = *(const float4*)&Bs[kk][tn << 2];
      float ar[4] = {a.x, a.y, a.z, a.w};
      float br[4] = {b.x, b.y, b.z, b.w};
#pragma unroll
      for (int i = 0; i < 4; ++i)
#pragma unroll
        for (int j = 0; j < 4; ++j) acc[i][j] += ar[i] * br[j];
    }
  }
#pragma unroll
  for (int i = 0; i < 4; ++i) {
    int m = m0 + (tm << 2) + i;
    if (m >= p.M) continue;
#pragma unroll
    for (int j = 0; j < 4; ++j) {
      int n = n0 + (tn << 2) + j;
      if (n >= p.N) continue;
      float v = acc[i][j];
      if (p.bias1) v += p.bias1[n];
      if (p.bias2) v += p.bias2[n];
      if (EPI == 1) {
        // m = pointer index, n = decode step t, z = batch
        float fl = B[(long long)n * p.ldb + DEMB];       // feat[.., 512]
        if (p.ft[z * NPTS + m] < n) v += fl;             // picked before step t
        v -= (1.0f - p.emb_mask[z * NPTS + m]) * 1e20f;  // emb mask
      }
      p.C[(long long)z * p.cBatch + (long long)m * p.ldcM + (long long)n * p.ldcN] = v;
    }
  }
}

// ---------------- fused LSTM step (t = 1..49) ----------------
// Each block: cell-update for its 8 batch rows from gates_{t-1}=XW[t-1] into LDS h,
// then accumulate h @ W_hh^T for its 64-j tile into XW[t] (in place).
// Only jt==0 blocks write c_{t-1} (parity buffer) and H[t-1].
__global__ __launch_bounds__(512) void k_lstm(const float* __restrict__ W_hh,
                                              float* __restrict__ XW,
                                              float* __restrict__ cbuf,
                                              float* __restrict__ H, int t) {
  __shared__ float hs[8][1028];  // +4 pad: conflict-free b128 reads
  const int bg = blockIdx.x & 3;   // 4 groups of 8 batch rows
  const int jt = blockIdx.x >> 2;  // 64 tiles of 64 gate rows
  const int tid = threadIdx.x;
  const float* gates = XW + (long long)(t - 1) * NB * G4;
  const float* cprev = cbuf + (t & 1) * NB * DDEC;        // c_{t-2}
  float* cnew = cbuf + ((t - 1) & 1) * NB * DDEC;         // c_{t-1}
  for (int r = tid; r < 8 * DDEC; r += 512) {
    int bb = r >> 10, u = r & (DDEC - 1);
    int b = bg * 8 + bb;
    const float* gb = gates + (long long)b * G4;
    float cp = (t == 1) ? 0.0f : cprev[b * DDEC + u];
    float cval = sigf(gb[DDEC + u]) * cp + sigf(gb[u]) * tanh_(gb[2 * DDEC + u]);
    float hval = sigf(gb[3 * DDEC + u]) * tanh_(cval);
    hs[bb][u] = hval;
    if (jt == 0) {
      cnew[b * DDEC + u] = cval;
      H[((long long)(t - 1) * NB + b) * DDEC + u] = hval;
    }
  }
  __syncthreads();
  const int j_l = tid >> 3, bb = tid & 7;
  const int j = jt * 64 + j_l;
  const int b = bg * 8 + bb;
  const float* wr = W_hh + (long long)j * DDEC;
  float acc = 0.0f;
#pragma unroll 4
  for (int k = 0; k < DDEC; k += 4) {
    float4 w = *(const float4*)(wr + k);
    float4 h4 = *(const float4*)&hs[bb][k];
    acc += w.x * h4.x + w.y * h4.y + w.z * h4.z + w.w * h4.w;
  }
  XW[(long long)t * NB * G4 + (long long)b * G4 + j] += acc;
}

// final cell update -> H[49]
__global__ void k_cell_final(const float* __restrict__ XW,
                             const float* __restrict__ cbuf,
                             float* __restrict__ H) {
  int idx = blockIdx.x * blockDim.x + threadIdx.x;
  if (idx >= NB * DDEC) return;
  int b = idx >> 10, u = idx & (DDEC - 1);
  const float* gb = XW + (long long)(TDEC - 1) * NB * G4 + (long long)b * G4;
  float cp = cbuf[0 * NB * DDEC + b * DDEC + u];  // c_48 lives at parity 0
  float cval = sigf(gb[DDEC + u]) * cp + sigf(gb[u]) * tanh_(gb[2 * DDEC + u]);
  H[((long long)(TDEC - 1) * NB + b) * DDEC + u] = sigf(gb[3 * DDEC + u]) * tanh_(cval);
}

// ---------------- masked softmax over T_ENC=512, in place ----------------
__global__ __launch_bounds__(256) void k_softmax(float* __restrict__ praw,
                                                 const float* __restrict__ enc_mask) {
  __shared__ float red[8];
  __shared__ float red2[8];
  int bt = blockIdx.x;           // b*50 + t
  int b = bt / TDEC;
  float* row = praw + (long long)bt * 512;
  int tid = threadIdx.x;
  float v0 = row[tid] - (1.0f - enc_mask[b * 512 + tid]) * 1e20f;
  float v1 = row[tid + 256] - (1.0f - enc_mask[b * 512 + tid + 256]) * 1e20f;
  float mx = fmaxf(v0, v1);
  for (int off = 32; off; off >>= 1) mx = fmaxf(mx, __shfl_xor(mx, off));
  if ((tid & 63) == 0) red[tid >> 6] = mx;
  __syncthreads();
  mx = fmaxf(fmaxf(red[0], red[1]), fmaxf(red[2], red[3]));
  float e0 = __expf(v0 - mx), e1 = __expf(v1 - mx);
  float s = e0 + e1;
  for (int off = 32; off; off >>= 1) s += __shfl_xor(s, off);
  if ((tid & 63) == 0) red2[tid >> 6] = s;
  __syncthreads();
  s = red2[0] + red2[1] + red2[2] + red2[3];
  float inv = 1.0f / s;
  row[tid] = e0 * inv;
  row[tid + 256] = e1 * inv;
}

// ---------------- host launcher ----------------
extern "C" void kernel_launch(void* const* d_in, const int* in_sizes, int n_in,
                              void* d_out, int out_size, void* d_ws, size_t ws_size,
                              hipStream_t stream) {
  const float* emb      = (const float*)d_in[0];
  const float* emb_mask = (const float*)d_in[1];
  const float* enc      = (const float*)d_in[2];
  const float* enc_mask = (const float*)d_in[3];
  const int*   gt       = (const int*)d_in[4];
  const float* go       = (const float*)d_in[5];
  const float* W_ih     = (const float*)d_in[6];
  const float* W_hh     = (const float*)d_in[7];
  const float* b_ih     = (const float*)d_in[8];
  const float* b_hh     = (const float*)d_in[9];
  const float* W_dec    = (const float*)d_in[10];
  const float* b_dec    = (const float*)d_in[11];
  const float* W_feat   = (const float*)d_in[12];
  const float* b_feat   = (const float*)d_in[13];
  float* out = (float*)d_out;

  char* base = (char*)d_ws;
  size_t off = 0;
  auto take = [&](size_t bytes) {
    char* p = base + off;
    off += (bytes + 255) & ~(size_t)255;
    return p;
  };
  float* Xin  = (float*)take((size_t)TDEC * NB * DEMB * 4);   // lstm inputs
  float* XW   = (float*)take((size_t)TDEC * NB * G4 * 4);     // pre-gates -> gates
  float* H    = (float*)take((size_t)TDEC * NB * DDEC * 4);   // all hidden states
  float* cbuf = (float*)take((size_t)2 * NB * DDEC * 4);      // c double buffer
  float* decb = (float*)take((size_t)TDEC * NB * DENC * 4);   // dec projections
  float* praw = (float*)take((size_t)NB * TDEC * 512 * 4);    // raw -> softmax p
  float* attn = (float*)take((size_t)TDEC * NB * DENC * 4);   // attention outputs
  float* feat = (float*)take((size_t)TDEC * NB * 516 * 4);    // feat (ld 516, 16B aligned)
  int*   ft   = (int*)  take((size_t)NB * NPTS * 4);          // first-occurrence of gt

  k_first<<<dim3((NB * NPTS + 255) / 256), dim3(256), 0, stream>>>(gt, ft);
  k_gather<<<dim3((TDEC * NB * DEMB + 255) / 256), dim3(256), 0, stream>>>(emb, gt, go, Xin);

  GemmP q;

  // XW = Xin @ W_ih^T + b_ih + b_hh     [1600 x 4096], K=512
  q = GemmP{Xin, 0, DEMB, nullptr, 0, DEMB,
            W_ih, 0, DEMB,
            XW, 0, G4, 1,
            TDEC * NB, G4, DEMB, b_ih, b_hh, nullptr, nullptr};
  k_gemm<true, 0><<<dim3(25, 64, 1), dim3(256), 0, stream>>>(q);

  // sequential LSTM: gates_t += h_{t-1} @ W_hh^T (gates_0 = XW[0] already)
  for (int t = 1; t < TDEC; ++t)
    k_lstm<<<dim3(256), dim3(512), 0, stream>>>(W_hh, XW, cbuf, H, t);
  k_cell_final<<<dim3(128), dim3(256), 0, stream>>>(XW, cbuf, H);

  // dec = H @ W_dec^T + b_dec           [1600 x 1024], K=1024
  q = GemmP{H, 0, DDEC, nullptr, 0, DDEC,
            W_dec, 0, DDEC,
            decb, 0, DENC, 1,
            TDEC * NB, DENC, DDEC, b_dec, nullptr, nullptr, nullptr};
  k_gemm<true, 0><<<dim3(25, 16, 1), dim3(256), 0, stream>>>(q);

  // raw[b] = dec[b] @ enc[b]^T          batched: [50 x 512], K=1024
  q = GemmP{decb, DENC, NB * DENC, nullptr, 0, NB * DENC,
            enc, (long long)512 * DENC, DENC,
            praw, (long long)TDEC * 512, 512, 1,
            TDEC, 512, DENC, nullptr, nullptr, nullptr, nullptr};
  k_gemm<true, 0><<<dim3(1, 8, 32), dim3(256), 0, stream>>>(q);

  // masked softmax rows (in place)
  k_softmax<<<dim3(NB * TDEC), dim3(256), 0, stream>>>(praw, enc_mask);

  // attn[b] = p[b] @ enc[b]             batched NN: [50 x 1024], K=512
  q = GemmP{praw, (long long)TDEC * 512, 512, nullptr, 0, 512,
            enc, (long long)512 * DENC, DENC,
            attn, DENC, (long long)NB * DENC, 1,
            TDEC, DENC, 512, nullptr, nullptr, nullptr, nullptr};
  k_gemm<false, 0><<<dim3(1, 16, 32), dim3(256), 0, stream>>>(q);

  // feat = [H, attn] @ W_feat^T + b_feat   [1600 x 513], K=2048 (split A)
  q = GemmP{H, 0, DDEC, attn, DENC, DDEC,
            W_feat, 0, DDEC + DENC,
            feat, 0, 516, 1,
            TDEC * NB, DEMB + 1, DDEC + DENC, b_feat, nullptr, nullptr, nullptr};
  k_gemm<true, 0><<<dim3(25, 9, 1), dim3(256), 0, stream>>>(q);

  // score[b,t,n] = emb[b] @ featd[b,t]^T + picked*feat_last - mask  -> out[b,t,n]
  q = GemmP{emb, (long long)NPTS * DEMB, DEMB, nullptr, 0, DEMB,
            feat, 516, NB * 516,
            out, (long long)TDEC * NPTS, 1, NPTS,
            NPTS, TDEC, DEMB, nullptr, nullptr, ft, emb_mask};
  k_gemm<true, 1><<<dim3(8, 1, 32), dim3(256), 0, stream>>>(q);
}